// Round 3
// baseline (160.405 us; speedup 1.0000x reference)
//
#include <hip/hip_runtime.h>
#include <hip/hip_bf16.h>

// Problem constants
#define BB 16
#define SS 1024
#define DD 384
#define HH 6
#define HDD 64
#define KK 9
#define KH 54      // K*H
#define NP 64      // KH padded to 64 for MFMA
#define OUTD 384

typedef __attribute__((ext_vector_type(4))) float floatx4;
typedef __attribute__((ext_vector_type(8))) __bf16 bf16x8;
typedef __attribute__((ext_vector_type(4))) __bf16 bf16x4;

#define QLD 392    // LDS leading dim (bf16): 784 B row -> 4-bank shift/row, <=2-way (free)

// ---------------------------------------------------------------------------
// Kernel 0: cast Wp -> bf16, Wk -> bf16 zero-padded to [64][384]
// ---------------------------------------------------------------------------
__global__ __launch_bounds__(256) void cast_kernel(const float* __restrict__ Wk,
                                                   const float* __restrict__ Wp,
                                                   __bf16* __restrict__ WkB,
                                                   __bf16* __restrict__ WpB) {
    int i = blockIdx.x * 256 + threadIdx.x;
    if (i < NP * DD) {
        int r = i / DD;
        WkB[i] = (r < KH) ? (__bf16)Wk[i] : (__bf16)0.0f;
    } else {
        int j = i - NP * DD;
        if (j < OUTD * DD) WpB[j] = (__bf16)Wp[j];
    }
}

// ---------------------------------------------------------------------------
// Kernel 1: fused  logits = (q*ks)@Wk^T + bk  -> softmax(9 taps) -> 9-tap conv
// Block = 64 seq rows (never crosses batch: 1024 % 64 == 0). 256 threads.
// qk staged once as bf16 (full K), single barrier; Wk B-frags direct from
// global (L2-hot); dk overlaid into logits LDS; conv reads v direct (L1 reuse).
// LDS = 50176 + 16896 = 67072 B -> 2 blocks/CU.
// ---------------------------------------------------------------------------
__global__ __launch_bounds__(256) void fused_kernel(const float* __restrict__ q,
                                                    const float* __restrict__ ks,
                                                    const float* __restrict__ v,
                                                    const __bf16* __restrict__ WkB,
                                                    const float* __restrict__ bk,
                                                    __bf16* __restrict__ outA) {
    __shared__ __bf16 qkS[64 * QLD];    // 50176 B
    __shared__ float  lgS[64 * 66];     // 16896 B; reused for dk[64][56] after softmax

    const int tid  = threadIdx.x;
    const int wave = tid >> 6;
    const int lane = tid & 63;
    const int m0   = blockIdx.x * 64;
    const int b    = blockIdx.x >> 4;         // 16 blocks per batch
    const int s0   = (blockIdx.x & 15) * 64;

    // ---- stage qk = q*ks as bf16, full 64x384 tile, no intermediate barrier ----
    const int sr = tid >> 2;                  // row 0..63
    const int sq = tid & 3;                   // col group
    {
        const float* qp = q  + (size_t)(m0 + sr) * DD + sq * 4;
        const float* kp = ks + (size_t)(m0 + sr) * DD + sq * 4;
        __bf16* dst = &qkS[sr * QLD + sq * 4];
#pragma unroll 6
        for (int c = 0; c < 24; ++c) {        // cols sq*4 + c*16
            floatx4 qv = *reinterpret_cast<const floatx4*>(qp + c * 16);
            floatx4 kv = *reinterpret_cast<const floatx4*>(kp + c * 16);
            floatx4 pr = qv * kv;
            bf16x4 pk = { (__bf16)pr.x, (__bf16)pr.y, (__bf16)pr.z, (__bf16)pr.w };
            *reinterpret_cast<bf16x4*>(dst + c * 16) = pk;
        }
    }
    __syncthreads();

    // ---- MFMA: logits tile 64x64, wave handles 16 rows; B-frags from global ----
    const int wm = wave * 16;
    const int fr = lane & 15;
    const int fk = (lane >> 4) * 8;
    floatx4 acc[4] = {};
#pragma unroll 4
    for (int kk = 0; kk < DD; kk += 32) {
        bf16x8 afrag = *reinterpret_cast<const bf16x8*>(&qkS[(wm + fr) * QLD + kk + fk]);
#pragma unroll
        for (int j = 0; j < 4; ++j) {
            bf16x8 bfrag = *reinterpret_cast<const bf16x8*>(
                WkB + (size_t)(j * 16 + fr) * DD + kk + fk);
            acc[j] = __builtin_amdgcn_mfma_f32_16x16x32_bf16(afrag, bfrag, acc[j], 0, 0, 0);
        }
    }

    // ---- logits -> LDS (C/D layout: col=lane&15, row=(lane>>4)*4+reg) ----
    const int col_in = lane & 15;
    const int rgrp   = (lane >> 4) * 4;
#pragma unroll
    for (int j = 0; j < 4; ++j)
#pragma unroll
        for (int r = 0; r < 4; ++r)
            lgS[(wm + rgrp + r) * 66 + j * 16 + col_in] = acc[j][r];
    __syncthreads();

    // ---- softmax over 9 taps: 384 (row,head) tasks, 2 rounds; dk into regs ----
    float dkv[2][KK];
#pragma unroll
    for (int rr = 0; rr < 2; ++rr) {
        int p = tid + rr * 256;
        if (p < 64 * HH) {
            int row = p / HH, h = p % HH;
            float mx = -1e30f;
#pragma unroll
            for (int k = 0; k < KK; ++k) {
                float s = lgS[row * 66 + h * KK + k] + bk[h * KK + k];
                dkv[rr][k] = s;
                mx = fmaxf(mx, s);
            }
            float sum = 0.0f;
#pragma unroll
            for (int k = 0; k < KK; ++k) { dkv[rr][k] = __expf(dkv[rr][k] - mx); sum += dkv[rr][k]; }
            float inv = 1.0f / sum;
#pragma unroll
            for (int k = 0; k < KK; ++k) dkv[rr][k] *= inv;
        }
    }
    __syncthreads();   // all lgS reads done; safe to overlay dk
    float* dkS = lgS;  // dk[64][56] overlaid
#pragma unroll
    for (int rr = 0; rr < 2; ++rr) {
        int p = tid + rr * 256;
        if (p < 64 * HH) {
            int row = p / HH, h = p % HH;
#pragma unroll
            for (int k = 0; k < KK; ++k) dkS[row * 56 + h * KK + k] = dkv[rr][k];
        }
    }
    __syncthreads();

    // ---- 9-tap conv: 64 rows x 96 float4-chunks; v direct from global ----
    const float* vb = v + (size_t)b * SS * DD;
    __bf16* ob = outA + (size_t)m0 * DD;
    const bool edge = (s0 == 0) || (s0 == SS - 64);
    if (!edge) {
#pragma unroll 2
        for (int it = 0; it < 24; ++it) {
            int tt = it * 256 + tid;
            int row = tt / 96, c4 = tt % 96;
            int h = c4 >> 4;
            const float* dkr = &dkS[row * 56 + h * KK];
            const float* vp = vb + (size_t)(s0 + row - 4) * DD + c4 * 4;
            floatx4 a = {};
#pragma unroll
            for (int k = 0; k < KK; ++k) {
                floatx4 w = *reinterpret_cast<const floatx4*>(vp + (size_t)k * DD);
                float dv = dkr[k];
                a += w * dv;
            }
            bf16x4 o = { (__bf16)a.x, (__bf16)a.y, (__bf16)a.z, (__bf16)a.w };
            *reinterpret_cast<bf16x4*>(&ob[(size_t)row * DD + c4 * 4]) = o;
        }
    } else {
#pragma unroll 2
        for (int it = 0; it < 24; ++it) {
            int tt = it * 256 + tid;
            int row = tt / 96, c4 = tt % 96;
            int h = c4 >> 4;
            const float* dkr = &dkS[row * 56 + h * KK];
            floatx4 a = {};
#pragma unroll
            for (int k = 0; k < KK; ++k) {
                int r = s0 + row - 4 + k;
                floatx4 w = {};
                if (r >= 0 && r < SS)
                    w = *reinterpret_cast<const floatx4*>(vb + (size_t)r * DD + c4 * 4);
                float dv = dkr[k];
                a += w * dv;
            }
            bf16x4 o = { (__bf16)a.x, (__bf16)a.y, (__bf16)a.z, (__bf16)a.w };
            *reinterpret_cast<bf16x4*>(&ob[(size_t)row * DD + c4 * 4]) = o;
        }
    }
}

// ---------------------------------------------------------------------------
// Kernel 2: C[16384][384] = A(bf16) @ Wp^T(bf16) + bp, fp32 out
// BM=128, BN=64. B-tile (64x384) staged ONCE to LDS; A-frags stream directly
// global->VGPR (L2-resident). ZERO barriers in the K-loop. 768 blocks, 3/CU.
// ---------------------------------------------------------------------------
__global__ __launch_bounds__(256) void gemm_kernel(const __bf16* __restrict__ A,
                                                   const __bf16* __restrict__ Bw,
                                                   const float* __restrict__ bias,
                                                   float* __restrict__ Cout) {
    __shared__ __bf16 Bs[64 * QLD];   // 50176 B -> 3 blocks/CU

    const int tid  = threadIdx.x;
    const int wave = tid >> 6;
    const int lane = tid & 63;

    const int mtile = blockIdx.x / (OUTD / 64);
    const int ntile = blockIdx.x % (OUTD / 64);
    const int m0 = mtile * 128;
    const int n0 = ntile * 64;

    // stage entire B tile: 64 rows x 384 cols bf16, 12 bf16x8 chunks/thread
#pragma unroll 4
    for (int j = 0; j < 12; ++j) {
        int id = tid + j * 256;
        int r = id / 48, ch = (id % 48) * 8;
        *reinterpret_cast<bf16x8*>(&Bs[r * QLD + ch]) =
            *reinterpret_cast<const bf16x8*>(Bw + (size_t)(n0 + r) * DD + ch);
    }
    __syncthreads();

    const int wm = wave * 32;           // wave owns 32 rows x all 64 cols
    const int fr = lane & 15;
    const int fk = (lane >> 4) * 8;

    floatx4 acc[2][4] = {};

#pragma unroll 4
    for (int kk = 0; kk < DD; kk += 32) {
        bf16x8 afrag[2];
#pragma unroll
        for (int i = 0; i < 2; ++i)
            afrag[i] = *reinterpret_cast<const bf16x8*>(
                A + (size_t)(m0 + wm + i * 16 + fr) * DD + kk + fk);
#pragma unroll
        for (int j = 0; j < 4; ++j) {
            bf16x8 bfrag = *reinterpret_cast<const bf16x8*>(&Bs[(j * 16 + fr) * QLD + kk + fk]);
#pragma unroll
            for (int i = 0; i < 2; ++i)
                acc[i][j] = __builtin_amdgcn_mfma_f32_16x16x32_bf16(afrag[i], bfrag, acc[i][j], 0, 0, 0);
        }
    }

    const int col_in = lane & 15;
    const int rgrp   = (lane >> 4) * 4;
#pragma unroll
    for (int i = 0; i < 2; ++i) {
#pragma unroll
        for (int j = 0; j < 4; ++j) {
            int col = n0 + j * 16 + col_in;
            float bv = bias[col];
#pragma unroll
            for (int r = 0; r < 4; ++r) {
                int row = m0 + wm + i * 16 + rgrp + r;
                Cout[(size_t)row * OUTD + col] = acc[i][j][r] + bv;
            }
        }
    }
}

// ---------------------------------------------------------------------------
extern "C" void kernel_launch(void* const* d_in, const int* in_sizes, int n_in,
                              void* d_out, int out_size, void* d_ws, size_t ws_size,
                              hipStream_t stream) {
    const float* q  = (const float*)d_in[0];
    const float* ks = (const float*)d_in[1];
    const float* v  = (const float*)d_in[2];
    const float* Wk = (const float*)d_in[3];
    const float* bk = (const float*)d_in[4];
    const float* Wp = (const float*)d_in[5];
    const float* bp = (const float*)d_in[6];
    float* out = (float*)d_out;

    // ws layout: WpB bf16 294912 B | WkB bf16 49152 B | A bf16 12582912 B
    __bf16* WpB = (__bf16*)d_ws;
    __bf16* WkB = (__bf16*)((char*)d_ws + 294912);
    __bf16* Abf = (__bf16*)((char*)d_ws + 294912 + 49152);

    cast_kernel<<<(NP * DD + OUTD * DD + 255) / 256, 256, 0, stream>>>(Wk, Wp, WkB, WpB);
    fused_kernel<<<(BB * SS) / 64, 256, 0, stream>>>(q, ks, v, WkB, bk, Abf);
    gemm_kernel<<<(BB * SS / 128) * (OUTD / 64), 256, 0, stream>>>(Abf, WpB, bp, out);
}

// Round 4
// 143.772 us; speedup vs baseline: 1.1157x; 1.1157x over previous
//
#include <hip/hip_runtime.h>
#include <hip/hip_bf16.h>

// Problem constants
#define BB 16
#define SS 1024
#define DD 384
#define HH 6
#define HDD 64
#define KK 9
#define KH 54      // K*H
#define NP 64      // KH padded to 64 for MFMA
#define OUTD 384

typedef __attribute__((ext_vector_type(4))) float floatx4;
typedef __attribute__((ext_vector_type(8))) __bf16 bf16x8;
typedef __attribute__((ext_vector_type(4))) __bf16 bf16x4;

#define QLD 392    // gemm B-tile LDS leading dim (bf16)
#define VLD 392    // fused kernel LDS leading dim (bf16): 784 B/row -> <=2-way (free)

// ---------------------------------------------------------------------------
// Kernel 0: cast Wp -> bf16, Wk -> bf16 zero-padded to [64][384]
// ---------------------------------------------------------------------------
__global__ __launch_bounds__(256) void cast_kernel(const float* __restrict__ Wk,
                                                   const float* __restrict__ Wp,
                                                   __bf16* __restrict__ WkB,
                                                   __bf16* __restrict__ WpB) {
    int i = blockIdx.x * 256 + threadIdx.x;
    if (i < NP * DD) {
        int r = i / DD;
        WkB[i] = (r < KH) ? (__bf16)Wk[i] : (__bf16)0.0f;
    } else {
        int j = i - NP * DD;
        if (j < OUTD * DD) WpB[j] = (__bf16)Wp[j];
    }
}

// ---------------------------------------------------------------------------
// Kernel 1: fused logits=(q*ks)@Wk^T+bk -> softmax(9) -> 9-tap conv -> A bf16
// Block = 32 seq rows, 256 threads, grid 512 (2 blocks/CU = 8 waves/CU).
// MFMA split: wave = (row-half, K-half); partials summed in softmax.
// v window staged once into LDS (overlays dead qk buffer).
// LDS = 31360 + 16896 + 7168 = 55424 B -> 2 blocks/CU.
// ---------------------------------------------------------------------------
__global__ __launch_bounds__(256) void fused_kernel(const float* __restrict__ q,
                                                    const float* __restrict__ ks,
                                                    const float* __restrict__ v,
                                                    const __bf16* __restrict__ WkB,
                                                    const float* __restrict__ bk,
                                                    __bf16* __restrict__ outA) {
    __shared__ __bf16 vqS[40 * VLD];       // 31360 B: qk tile (rows 0..31), then v window (rows 0..39)
    __shared__ float  lgS[2 * 32 * 66];    // 16896 B: two K-half partial logit tiles
    __shared__ float  dkS[32 * 56];        // 7168 B: softmaxed taps

    const int tid  = threadIdx.x;
    const int wave = tid >> 6;
    const int lane = tid & 63;
    const int m0   = blockIdx.x * 32;
    const int b    = blockIdx.x >> 5;          // 32 blocks per batch
    const int s0   = (blockIdx.x & 31) * 32;

    // ---- phase 1: stage qk = q*ks as bf16, 32x384, coalesced ----
    {
        const float* qb = q  + (size_t)m0 * DD;
        const float* kb = ks + (size_t)m0 * DD;
#pragma unroll
        for (int it = 0; it < 12; ++it) {
            int c = tid + it * 256;            // 0..3071
            int row = c / 96, col = (c % 96) * 4;
            floatx4 qv = *reinterpret_cast<const floatx4*>(qb + (size_t)row * DD + col);
            floatx4 kv = *reinterpret_cast<const floatx4*>(kb + (size_t)row * DD + col);
            floatx4 pr = qv * kv;
            bf16x4 pk = { (__bf16)pr.x, (__bf16)pr.y, (__bf16)pr.z, (__bf16)pr.w };
            *reinterpret_cast<bf16x4*>(&vqS[row * VLD + col]) = pk;
        }
    }
    __syncthreads();

    // ---- phase 2: MFMA logits. wave: rows (wave&1)*16, K-half (wave>>1) ----
    {
        const int wm = (wave & 1) * 16;
        const int kh = wave >> 1;
        const int fr = lane & 15;
        const int fk = (lane >> 4) * 8;
        floatx4 acc[4] = {};
#pragma unroll
        for (int s = 0; s < 6; ++s) {
            int kk = kh * 192 + s * 32;
            bf16x8 afrag = *reinterpret_cast<const bf16x8*>(&vqS[(wm + fr) * VLD + kk + fk]);
#pragma unroll
            for (int j = 0; j < 4; ++j) {
                bf16x8 bfrag = *reinterpret_cast<const bf16x8*>(
                    WkB + (size_t)(j * 16 + fr) * DD + kk + fk);
                acc[j] = __builtin_amdgcn_mfma_f32_16x16x32_bf16(afrag, bfrag, acc[j], 0, 0, 0);
            }
        }
        // partials to LDS (C/D layout: col=lane&15, row=(lane>>4)*4+reg)
        const int col_in = lane & 15;
        const int rgrp   = (lane >> 4) * 4;
#pragma unroll
        for (int j = 0; j < 4; ++j)
#pragma unroll
            for (int r = 0; r < 4; ++r)
                lgS[(kh * 32 + wm + rgrp + r) * 66 + j * 16 + col_in] = acc[j][r];
    }
    __syncthreads();

    // ---- phase 3a: softmax over 9 taps (192 tasks; sums the two K-partials) ----
    if (tid < 32 * HH) {
        int row = tid / HH, h = tid % HH;
        float lg[KK];
        float mx = -1e30f;
#pragma unroll
        for (int k = 0; k < KK; ++k) {
            int o = h * KK + k;
            float s = lgS[row * 66 + o] + lgS[(32 + row) * 66 + o] + bk[o];
            lg[k] = s;
            mx = fmaxf(mx, s);
        }
        float sum = 0.0f;
#pragma unroll
        for (int k = 0; k < KK; ++k) { lg[k] = __expf(lg[k] - mx); sum += lg[k]; }
        float inv = 1.0f / sum;
#pragma unroll
        for (int k = 0; k < KK; ++k) dkS[row * 56 + h * KK + k] = lg[k] * inv;
    }

    // ---- phase 3b: stage v window rows s0-4..s0+35 as bf16 (overlay qk) ----
    {
        const float* vb = v + (size_t)b * SS * DD;
#pragma unroll
        for (int it = 0; it < 15; ++it) {
            int c = tid + it * 256;            // 0..3839
            int row = c / 96, col = (c % 96) * 4;
            int r = s0 + row - 4;
            floatx4 val = {};
            if (r >= 0 && r < SS)
                val = *reinterpret_cast<const floatx4*>(vb + (size_t)r * DD + col);
            bf16x4 vk = { (__bf16)val.x, (__bf16)val.y, (__bf16)val.z, (__bf16)val.w };
            *reinterpret_cast<bf16x4*>(&vqS[row * VLD + col]) = vk;
        }
    }
    __syncthreads();

    // ---- phase 4: 9-tap conv from LDS, write A bf16, coalesced ----
    __bf16* ob = outA + (size_t)m0 * DD;
#pragma unroll
    for (int it = 0; it < 12; ++it) {
        int p = tid + it * 256;                // 0..3071
        int row = p / 96, c4 = p % 96;
        int h = c4 >> 4;
        const float* dkr = &dkS[row * 56 + h * KK];
        floatx4 a = {};
#pragma unroll
        for (int k = 0; k < KK; ++k) {
            bf16x4 w = *reinterpret_cast<const bf16x4*>(&vqS[(row + k) * VLD + c4 * 4]);
            floatx4 wf = { (float)w[0], (float)w[1], (float)w[2], (float)w[3] };
            a += wf * dkr[k];
        }
        bf16x4 o = { (__bf16)a.x, (__bf16)a.y, (__bf16)a.z, (__bf16)a.w };
        *reinterpret_cast<bf16x4*>(&ob[(size_t)row * DD + c4 * 4]) = o;
    }
}

// ---------------------------------------------------------------------------
// Kernel 2: C[16384][384] = A(bf16) @ Wp^T(bf16) + bp, fp32 out
// BM=128, BN=64. B-tile (64x384) staged ONCE to LDS; A-frags stream directly
// global->VGPR (L2-resident). ZERO barriers in the K-loop. 768 blocks, 3/CU.
// ---------------------------------------------------------------------------
__global__ __launch_bounds__(256) void gemm_kernel(const __bf16* __restrict__ A,
                                                   const __bf16* __restrict__ Bw,
                                                   const float* __restrict__ bias,
                                                   float* __restrict__ Cout) {
    __shared__ __bf16 Bs[64 * QLD];   // 50176 B -> 3 blocks/CU

    const int tid  = threadIdx.x;
    const int wave = tid >> 6;
    const int lane = tid & 63;

    const int mtile = blockIdx.x / (OUTD / 64);
    const int ntile = blockIdx.x % (OUTD / 64);
    const int m0 = mtile * 128;
    const int n0 = ntile * 64;

    // stage entire B tile: 64 rows x 384 cols bf16
#pragma unroll 4
    for (int j = 0; j < 12; ++j) {
        int id = tid + j * 256;
        int r = id / 48, ch = (id % 48) * 8;
        *reinterpret_cast<bf16x8*>(&Bs[r * QLD + ch]) =
            *reinterpret_cast<const bf16x8*>(Bw + (size_t)(n0 + r) * DD + ch);
    }
    __syncthreads();

    const int wm = wave * 32;
    const int fr = lane & 15;
    const int fk = (lane >> 4) * 8;

    floatx4 acc[2][4] = {};

#pragma unroll 4
    for (int kk = 0; kk < DD; kk += 32) {
        bf16x8 afrag[2];
#pragma unroll
        for (int i = 0; i < 2; ++i)
            afrag[i] = *reinterpret_cast<const bf16x8*>(
                A + (size_t)(m0 + wm + i * 16 + fr) * DD + kk + fk);
#pragma unroll
        for (int j = 0; j < 4; ++j) {
            bf16x8 bfrag = *reinterpret_cast<const bf16x8*>(&Bs[(j * 16 + fr) * QLD + kk + fk]);
#pragma unroll
            for (int i = 0; i < 2; ++i)
                acc[i][j] = __builtin_amdgcn_mfma_f32_16x16x32_bf16(afrag[i], bfrag, acc[i][j], 0, 0, 0);
        }
    }

    const int col_in = lane & 15;
    const int rgrp   = (lane >> 4) * 4;
#pragma unroll
    for (int i = 0; i < 2; ++i) {
#pragma unroll
        for (int j = 0; j < 4; ++j) {
            int col = n0 + j * 16 + col_in;
            float bv = bias[col];
#pragma unroll
            for (int r = 0; r < 4; ++r) {
                int row = m0 + wm + i * 16 + rgrp + r;
                Cout[(size_t)row * OUTD + col] = acc[i][j][r] + bv;
            }
        }
    }
}

// ---------------------------------------------------------------------------
extern "C" void kernel_launch(void* const* d_in, const int* in_sizes, int n_in,
                              void* d_out, int out_size, void* d_ws, size_t ws_size,
                              hipStream_t stream) {
    const float* q  = (const float*)d_in[0];
    const float* ks = (const float*)d_in[1];
    const float* v  = (const float*)d_in[2];
    const float* Wk = (const float*)d_in[3];
    const float* bk = (const float*)d_in[4];
    const float* Wp = (const float*)d_in[5];
    const float* bp = (const float*)d_in[6];
    float* out = (float*)d_out;

    // ws layout: WpB bf16 294912 B | WkB bf16 49152 B | A bf16 12582912 B
    __bf16* WpB = (__bf16*)d_ws;
    __bf16* WkB = (__bf16*)((char*)d_ws + 294912);
    __bf16* Abf = (__bf16*)((char*)d_ws + 294912 + 49152);

    cast_kernel<<<(NP * DD + OUTD * DD + 255) / 256, 256, 0, stream>>>(Wk, Wp, WkB, WpB);
    fused_kernel<<<(BB * SS) / 32, 256, 0, stream>>>(q, ks, v, WkB, bk, Abf);
    gemm_kernel<<<(BB * SS / 128) * (OUTD / 64), 256, 0, stream>>>(Abf, WpB, bp, out);
}

// Round 5
// 130.141 us; speedup vs baseline: 1.2325x; 1.1047x over previous
//
#include <hip/hip_runtime.h>
#include <hip/hip_bf16.h>

// Problem constants
#define BB 16
#define SS 1024
#define DD 384
#define HH 6
#define KK 9
#define KH 54      // K*H
#define OUTD 384
#define NKT 12     // K-steps: 384/32
#define VLD 392    // LDS leading dim (bf16): 784 B/row -> <=2-way bank aliasing (free)

typedef __attribute__((ext_vector_type(4))) float floatx4;
typedef __attribute__((ext_vector_type(8))) __bf16 bf16x8;
typedef __attribute__((ext_vector_type(4))) __bf16 bf16x4;

// ---------------------------------------------------------------------------
// Kernel 0: cast + swizzle weights into MFMA B-fragment order.
// WkT: 4 ntiles (54 rows zero-padded to 64) x 12 ksteps x 64 lanes x 8 bf16.
// WpT: 24 ntiles x 12 ksteps x 64 lanes x 8 bf16.
// Fragment: lane = n_in_tile(0..15) + 16*(k_quad); elems = 8 consecutive k.
// Every MFMA B-load becomes ONE lane-contiguous 1-KB transaction.
// ---------------------------------------------------------------------------
__global__ __launch_bounds__(256) void cast_kernel(const float* __restrict__ Wk,
                                                   const float* __restrict__ Wp,
                                                   __bf16* __restrict__ WkT,
                                                   __bf16* __restrict__ WpT) {
    int i = blockIdx.x * 256 + threadIdx.x;
    if (i < 4 * NKT * 64 * 8) {                    // 24576 elems of WkT
        int e = i & 7, lane = (i >> 3) & 63, t = i >> 9;
        int kstep = t % NKT, ntile = t / NKT;
        int row = ntile * 16 + (lane & 15);
        int col = kstep * 32 + ((lane >> 4) << 3) + e;
        WkT[i] = (row < KH) ? (__bf16)Wk[row * DD + col] : (__bf16)0.0f;
    } else if (i < 24576 + 24 * NKT * 64 * 8) {    // 147456 elems of WpT
        int j = i - 24576;
        int e = j & 7, lane = (j >> 3) & 63, t = j >> 9;
        int kstep = t % NKT, ntile = t / NKT;
        int row = ntile * 16 + (lane & 15);
        int col = kstep * 32 + ((lane >> 4) << 3) + e;
        WpT[j] = (__bf16)Wp[row * DD + col];
    }
}

// ---------------------------------------------------------------------------
// Kernel 1: FULLY fused: logits=(q*ks)@Wk^T+bk -> softmax(9) -> 9-tap conv
//           -> A-tile in LDS -> C = A @ Wp^T + bp  (fp32 out)
// Block = 32 seq rows, 256 threads; grid 512 -> 2 blocks/CU (8 waves/CU).
// LDS: vqS 31360 (qk tile, then v window) + dkS 7168 + union(lgS 16896 /
// aS 25088) = 63616 B. A never touches HBM.
// ---------------------------------------------------------------------------
__global__ __launch_bounds__(256) void fused_kernel(const float* __restrict__ q,
                                                    const float* __restrict__ ks,
                                                    const float* __restrict__ v,
                                                    const __bf16* __restrict__ WkT,
                                                    const float* __restrict__ bk,
                                                    const __bf16* __restrict__ WpT,
                                                    const float* __restrict__ bp,
                                                    float* __restrict__ out) {
    __shared__ __bf16 vqS[40 * VLD];                   // 31360 B
    __shared__ float  dkS[32 * 56];                    //  7168 B
    __shared__ __align__(16) char uS[32 * VLD * 2];    // 25088 B: lgS, later aS
    float*  lgS = (float*)uS;                          // [64][66] K-half partials
    __bf16* aS  = (__bf16*)uS;                         // [32][VLD] conv output

    const int tid  = threadIdx.x;
    const int wave = tid >> 6;
    const int lane = tid & 63;
    const int m0   = blockIdx.x * 32;
    const int b    = blockIdx.x >> 5;                  // 32 blocks per batch
    const int s0   = (blockIdx.x & 31) * 32;
    const int fr   = lane & 15;
    const int fk   = (lane >> 4) * 8;
    const int col_in = lane & 15;
    const int rgrp   = (lane >> 4) * 4;

    // ---- phase 1: stage qk = q*ks as bf16, 32x384, coalesced ----
    {
        const float* qb = q  + (size_t)m0 * DD;
        const float* kb = ks + (size_t)m0 * DD;
#pragma unroll
        for (int it = 0; it < 12; ++it) {
            int c = tid + it * 256;
            int row = c / 96, col = (c % 96) * 4;
            floatx4 qv = *reinterpret_cast<const floatx4*>(qb + (size_t)row * DD + col);
            floatx4 kv = *reinterpret_cast<const floatx4*>(kb + (size_t)row * DD + col);
            floatx4 pr = qv * kv;
            bf16x4 pk = { (__bf16)pr.x, (__bf16)pr.y, (__bf16)pr.z, (__bf16)pr.w };
            *reinterpret_cast<bf16x4*>(&vqS[row * VLD + col]) = pk;
        }
    }
    __syncthreads();

    // ---- phase 2: logits MFMA; wave = (row-half, K-half); swizzled WkT ----
    {
        const int wml = (wave & 1) * 16;
        const int kh  = wave >> 1;
        floatx4 acc[4] = {};
#pragma unroll
        for (int s = 0; s < 6; ++s) {
            int kst = kh * 6 + s;
            bf16x8 af = *reinterpret_cast<const bf16x8*>(&vqS[(wml + fr) * VLD + kst * 32 + fk]);
#pragma unroll
            for (int j = 0; j < 4; ++j) {
                bf16x8 bf = *reinterpret_cast<const bf16x8*>(
                    WkT + (((j * NKT + kst) * 64 + lane) << 3));
                acc[j] = __builtin_amdgcn_mfma_f32_16x16x32_bf16(af, bf, acc[j], 0, 0, 0);
            }
        }
        // C/D layout: col = lane&15, row = (lane>>4)*4 + reg
#pragma unroll
        for (int j = 0; j < 4; ++j)
#pragma unroll
            for (int r = 0; r < 4; ++r)
                lgS[(kh * 32 + wml + rgrp + r) * 66 + j * 16 + col_in] = acc[j][r];
    }
    __syncthreads();

    // ---- phase 3a: softmax over 9 taps (192 tasks; sums K-half partials) ----
    if (tid < 32 * HH) {
        int row = tid / HH, h = tid % HH;
        float lg[KK];
        float mx = -1e30f;
#pragma unroll
        for (int k = 0; k < KK; ++k) {
            int o = h * KK + k;
            float s = lgS[row * 66 + o] + lgS[(32 + row) * 66 + o] + bk[o];
            lg[k] = s;
            mx = fmaxf(mx, s);
        }
        float sum = 0.0f;
#pragma unroll
        for (int k = 0; k < KK; ++k) { lg[k] = __expf(lg[k] - mx); sum += lg[k]; }
        float inv = 1.0f / sum;
#pragma unroll
        for (int k = 0; k < KK; ++k) dkS[row * 56 + h * KK + k] = lg[k] * inv;
    }
    // ---- phase 3b: stage v window rows s0-4..s0+35 as bf16 (overlay qk) ----
    {
        const float* vb = v + (size_t)b * SS * DD;
#pragma unroll
        for (int it = 0; it < 15; ++it) {
            int c = tid + it * 256;
            int row = c / 96, col = (c % 96) * 4;
            int r = s0 + row - 4;
            floatx4 val = {};
            if (r >= 0 && r < SS)
                val = *reinterpret_cast<const floatx4*>(vb + (size_t)r * DD + col);
            bf16x4 vk = { (__bf16)val.x, (__bf16)val.y, (__bf16)val.z, (__bf16)val.w };
            *reinterpret_cast<bf16x4*>(&vqS[row * VLD + col]) = vk;
        }
    }
    __syncthreads();

    // ---- phase 4: 9-tap conv from LDS -> A-tile in LDS (overlays lgS) ----
#pragma unroll
    for (int it = 0; it < 12; ++it) {
        int p = tid + it * 256;
        int row = p / 96, c4 = p % 96;
        int h = c4 >> 4;
        const float* dkr = &dkS[row * 56 + h * KK];
        floatx4 a = {};
#pragma unroll
        for (int k = 0; k < KK; ++k) {
            bf16x4 w = *reinterpret_cast<const bf16x4*>(&vqS[(row + k) * VLD + c4 * 4]);
            floatx4 wf = { (float)w[0], (float)w[1], (float)w[2], (float)w[3] };
            a += wf * dkr[k];
        }
        bf16x4 o = { (__bf16)a.x, (__bf16)a.y, (__bf16)a.z, (__bf16)a.w };
        *reinterpret_cast<bf16x4*>(&aS[row * VLD + c4 * 4]) = o;
    }
    __syncthreads();

    // ---- phase 5: C = A @ Wp^T + bp. wave = (row-half 16, col-half 192).
    //      A-frags from LDS (ds_read_b128), B-frags 1-KB coalesced from WpT.
    {
        const int wm  = (wave & 1) * 16;
        const int nt0 = (wave >> 1) * 12;
        floatx4 acc[12] = {};
#pragma unroll 2
        for (int s = 0; s < NKT; ++s) {
            bf16x8 af = *reinterpret_cast<const bf16x8*>(&aS[(wm + fr) * VLD + s * 32 + fk]);
#pragma unroll
            for (int j = 0; j < 12; ++j) {
                bf16x8 bf = *reinterpret_cast<const bf16x8*>(
                    WpT + ((((nt0 + j) * NKT + s) * 64 + lane) << 3));
                acc[j] = __builtin_amdgcn_mfma_f32_16x16x32_bf16(af, bf, acc[j], 0, 0, 0);
            }
        }
        float* ob = out + (size_t)m0 * OUTD;
#pragma unroll
        for (int j = 0; j < 12; ++j) {
            int col = (nt0 + j) * 16 + col_in;
            float bv = bp[col];
#pragma unroll
            for (int r = 0; r < 4; ++r)
                ob[(size_t)(wm + rgrp + r) * OUTD + col] = acc[j][r] + bv;
        }
    }
}

// ---------------------------------------------------------------------------
extern "C" void kernel_launch(void* const* d_in, const int* in_sizes, int n_in,
                              void* d_out, int out_size, void* d_ws, size_t ws_size,
                              hipStream_t stream) {
    const float* q  = (const float*)d_in[0];
    const float* ks = (const float*)d_in[1];
    const float* v  = (const float*)d_in[2];
    const float* Wk = (const float*)d_in[3];
    const float* bk = (const float*)d_in[4];
    const float* Wp = (const float*)d_in[5];
    const float* bp = (const float*)d_in[6];
    float* out = (float*)d_out;

    // ws layout: WkT bf16 49152 B | WpT bf16 294912 B
    __bf16* WkT = (__bf16*)d_ws;
    __bf16* WpT = (__bf16*)((char*)d_ws + 49152);

    cast_kernel<<<(24576 + 147456 + 255) / 256, 256, 0, stream>>>(Wk, Wp, WkT, WpT);
    fused_kernel<<<(BB * SS) / 32, 256, 0, stream>>>(q, ks, v, WkT, bk, WpT, bp, out);
}

// Round 6
// 126.725 us; speedup vs baseline: 1.2658x; 1.0270x over previous
//
#include <hip/hip_runtime.h>
#include <hip/hip_bf16.h>

// Problem constants
#define BB 16
#define SS 1024
#define DD 384
#define HH 6
#define KK 9
#define KH 54      // K*H
#define OUTD 384
#define NKT 12     // K-steps: 384/32
#define VLD 392    // LDS leading dim (bf16): 784 B/row -> 4-bank shift/row, <=2-way (free)

typedef __attribute__((ext_vector_type(4))) float floatx4;
typedef __attribute__((ext_vector_type(8))) __bf16 bf16x8;
typedef __attribute__((ext_vector_type(4))) __bf16 bf16x4;

// ---------------------------------------------------------------------------
// Kernel 0: cast + swizzle weights into MFMA B-fragment order.
// WkT: 4 ntiles (54 rows zero-padded to 64) x 12 ksteps x 64 lanes x 8 bf16.
// WpT: 24 ntiles x 12 ksteps x 64 lanes x 8 bf16.
// Fragment: lane = n_in_tile(0..15) + 16*k_quad; elems = 8 consecutive k.
// Every MFMA B-load is ONE lane-contiguous 1-KB transaction (L2-resident).
// ---------------------------------------------------------------------------
__global__ __launch_bounds__(256) void cast_kernel(const float* __restrict__ Wk,
                                                   const float* __restrict__ Wp,
                                                   __bf16* __restrict__ WkT,
                                                   __bf16* __restrict__ WpT) {
    int i = blockIdx.x * 256 + threadIdx.x;
    if (i < 4 * NKT * 64 * 8) {                    // 24576 elems of WkT
        int e = i & 7, lane = (i >> 3) & 63, t = i >> 9;
        int kstep = t % NKT, ntile = t / NKT;
        int row = ntile * 16 + (lane & 15);
        int col = kstep * 32 + ((lane >> 4) << 3) + e;
        WkT[i] = (row < KH) ? (__bf16)Wk[row * DD + col] : (__bf16)0.0f;
    } else if (i < 24576 + 24 * NKT * 64 * 8) {    // 147456 elems of WpT
        int j = i - 24576;
        int e = j & 7, lane = (j >> 3) & 63, t = j >> 9;
        int kstep = t % NKT, ntile = t / NKT;
        int row = ntile * 16 + (lane & 15);
        int col = kstep * 32 + ((lane >> 4) << 3) + e;
        WpT[j] = (__bf16)Wp[row * DD + col];
    }
}

// ---------------------------------------------------------------------------
// Kernel 1: FULLY fused. Block = 16 seq rows, 256 threads, grid 1024.
// LDS = 18816 (vqS: qk rows 0..15, then v rows 0..23) + 3584 (dkS)
//     + union(lgS 4224 / aS 12544) = 34944 B  ->  4 blocks/CU, ALL 1024
// blocks co-resident (16 waves/CU). Weights read ONCE per block.
// ---------------------------------------------------------------------------
__global__ __launch_bounds__(256, 4) void fused_kernel(const float* __restrict__ q,
                                                       const float* __restrict__ ks,
                                                       const float* __restrict__ v,
                                                       const __bf16* __restrict__ WkT,
                                                       const float* __restrict__ bk,
                                                       const __bf16* __restrict__ WpT,
                                                       const float* __restrict__ bp,
                                                       float* __restrict__ out) {
    __shared__ __bf16 vqS[24 * VLD];                   // 18816 B
    __shared__ float  dkS[16 * 56];                    //  3584 B
    __shared__ __align__(16) char uS[16 * VLD * 2];    // 12544 B: lgS, later aS
    float*  lgS = (float*)uS;                          // [16][66] logits
    __bf16* aS  = (__bf16*)uS;                         // [16][VLD] conv output

    const int tid  = threadIdx.x;
    const int wave = tid >> 6;
    const int lane = tid & 63;
    const int m0   = blockIdx.x * 16;
    const int b    = blockIdx.x >> 6;                  // 64 blocks per batch
    const int s0   = (blockIdx.x & 63) * 16;
    const int fr   = lane & 15;
    const int fk   = (lane >> 4) * 8;
    const int col_in = lane & 15;
    const int rgrp   = (lane >> 4) * 4;

    // ---- phase 1: stage qk = q*ks as bf16, 16x384, coalesced ----
    {
        const float* qb = q  + (size_t)m0 * DD;
        const float* kb = ks + (size_t)m0 * DD;
#pragma unroll
        for (int it = 0; it < 6; ++it) {
            int c = tid + it * 256;                    // 0..1535 float4-chunks
            int row = c / 96, col = (c % 96) * 4;
            floatx4 qv = *reinterpret_cast<const floatx4*>(qb + (size_t)row * DD + col);
            floatx4 kv = *reinterpret_cast<const floatx4*>(kb + (size_t)row * DD + col);
            floatx4 pr = qv * kv;
            bf16x4 pk = { (__bf16)pr.x, (__bf16)pr.y, (__bf16)pr.z, (__bf16)pr.w };
            *reinterpret_cast<bf16x4*>(&vqS[row * VLD + col]) = pk;
        }
    }
    __syncthreads();

    // ---- phase 2: logits MFMA. wave = ntile (full K, WkT read once/block) ----
    {
        floatx4 acc = {};
#pragma unroll
        for (int s = 0; s < NKT; ++s) {
            bf16x8 af = *reinterpret_cast<const bf16x8*>(&vqS[fr * VLD + s * 32 + fk]);
            bf16x8 bf = *reinterpret_cast<const bf16x8*>(
                WkT + (((wave * NKT + s) * 64 + lane) << 3));
            acc = __builtin_amdgcn_mfma_f32_16x16x32_bf16(af, bf, acc, 0, 0, 0);
        }
        // C/D layout: col = lane&15, row = (lane>>4)*4 + reg
#pragma unroll
        for (int r = 0; r < 4; ++r)
            lgS[(rgrp + r) * 66 + wave * 16 + col_in] = acc[r];
    }
    __syncthreads();

    // ---- phase 3a: softmax over 9 taps (96 tasks) -> dkS ----
    if (tid < 16 * HH) {
        int row = tid / HH, h = tid % HH;
        float lg[KK];
        float mx = -1e30f;
#pragma unroll
        for (int k = 0; k < KK; ++k) {
            float s = lgS[row * 66 + h * KK + k] + bk[h * KK + k];
            lg[k] = s;
            mx = fmaxf(mx, s);
        }
        float sum = 0.0f;
#pragma unroll
        for (int k = 0; k < KK; ++k) { lg[k] = __expf(lg[k] - mx); sum += lg[k]; }
        float inv = 1.0f / sum;
#pragma unroll
        for (int k = 0; k < KK; ++k) dkS[row * 56 + h * KK + k] = lg[k] * inv;
    }

    // ---- phase 3b: stage v window rows s0-4..s0+19 as bf16 (overlay qk) ----
    {
        const float* vb = v + (size_t)b * SS * DD;
        if (s0 != 0 && s0 != SS - 16) {
#pragma unroll
            for (int it = 0; it < 9; ++it) {
                int c = tid + it * 256;                // 0..2303 float4-chunks
                int row = c / 96, col = (c % 96) * 4;
                floatx4 val = *reinterpret_cast<const floatx4*>(
                    vb + (size_t)(s0 + row - 4) * DD + col);
                bf16x4 vk = { (__bf16)val.x, (__bf16)val.y, (__bf16)val.z, (__bf16)val.w };
                *reinterpret_cast<bf16x4*>(&vqS[row * VLD + col]) = vk;
            }
        } else {
#pragma unroll
            for (int it = 0; it < 9; ++it) {
                int c = tid + it * 256;
                int row = c / 96, col = (c % 96) * 4;
                int r = s0 + row - 4;
                floatx4 val = {};
                if (r >= 0 && r < SS)
                    val = *reinterpret_cast<const floatx4*>(vb + (size_t)r * DD + col);
                bf16x4 vk = { (__bf16)val.x, (__bf16)val.y, (__bf16)val.z, (__bf16)val.w };
                *reinterpret_cast<bf16x4*>(&vqS[row * VLD + col]) = vk;
            }
        }
    }
    __syncthreads();

    // ---- phase 4: 9-tap conv from LDS -> A-tile in LDS (overlays lgS) ----
#pragma unroll
    for (int it = 0; it < 6; ++it) {
        int p = tid + it * 256;                        // 0..1535
        int row = p / 96, c4 = p % 96;
        int h = c4 >> 4;
        const float* dkr = &dkS[row * 56 + h * KK];
        floatx4 a = {};
#pragma unroll
        for (int k = 0; k < KK; ++k) {
            bf16x4 w = *reinterpret_cast<const bf16x4*>(&vqS[(row + k) * VLD + c4 * 4]);
            floatx4 wf = { (float)w[0], (float)w[1], (float)w[2], (float)w[3] };
            a += wf * dkr[k];
        }
        bf16x4 o = { (__bf16)a.x, (__bf16)a.y, (__bf16)a.z, (__bf16)a.w };
        *reinterpret_cast<bf16x4*>(&aS[row * VLD + c4 * 4]) = o;
    }
    __syncthreads();

    // ---- phase 5: C = A @ Wp^T + bp. wave = col-quarter (6 ntiles), M=16.
    //      WpT read ONCE per block; A-frags via ds_read_b128.
    {
        const int nt0 = wave * 6;
        floatx4 acc[6] = {};
#pragma unroll
        for (int s = 0; s < NKT; ++s) {
            bf16x8 af = *reinterpret_cast<const bf16x8*>(&aS[fr * VLD + s * 32 + fk]);
#pragma unroll
            for (int j = 0; j < 6; ++j) {
                bf16x8 bf = *reinterpret_cast<const bf16x8*>(
                    WpT + ((((nt0 + j) * NKT + s) * 64 + lane) << 3));
                acc[j] = __builtin_amdgcn_mfma_f32_16x16x32_bf16(af, bf, acc[j], 0, 0, 0);
            }
        }
        float* ob = out + (size_t)m0 * OUTD;
#pragma unroll
        for (int j = 0; j < 6; ++j) {
            int col = (nt0 + j) * 16 + col_in;
            float bv = bp[col];
#pragma unroll
            for (int r = 0; r < 4; ++r)
                ob[(size_t)(rgrp + r) * OUTD + col] = acc[j][r] + bv;
        }
    }
}

// ---------------------------------------------------------------------------
extern "C" void kernel_launch(void* const* d_in, const int* in_sizes, int n_in,
                              void* d_out, int out_size, void* d_ws, size_t ws_size,
                              hipStream_t stream) {
    const float* q  = (const float*)d_in[0];
    const float* ks = (const float*)d_in[1];
    const float* v  = (const float*)d_in[2];
    const float* Wk = (const float*)d_in[3];
    const float* bk = (const float*)d_in[4];
    const float* Wp = (const float*)d_in[5];
    const float* bp = (const float*)d_in[6];
    float* out = (float*)d_out;

    // ws layout: WkT bf16 49152 B | WpT bf16 294912 B
    __bf16* WkT = (__bf16*)d_ws;
    __bf16* WpT = (__bf16*)((char*)d_ws + 49152);

    cast_kernel<<<(24576 + 147456 + 255) / 256, 256, 0, stream>>>(Wk, Wp, WkT, WpT);
    fused_kernel<<<(BB * SS) / 16, 256, 0, stream>>>(q, ks, v, WkT, bk, WpT, bp, out);
}